// Round 1
// baseline (1790.294 us; speedup 1.0000x reference)
//
#include <hip/hip_runtime.h>

#define B 32
#define S 2048
#define I 256
#define H 256

typedef _Float16 h2 __attribute__((ext_vector_type(2)));
typedef _Float16 h8 __attribute__((ext_vector_type(8)));

__device__ __forceinline__ float fdot2(h2 a, h2 b, float c) {
#if __has_builtin(__builtin_amdgcn_fdot2)
    return __builtin_amdgcn_fdot2(a, b, c, false);
#else
    return fmaf((float)a[1], (float)b[1], fmaf((float)a[0], (float)b[0], c));
#endif
}

// ---------------------------------------------------------------------------
// Phase 1: xw[m][n] = sum_k x[m][k] * Wxw[n][k] + Wxb[n]
// M = B*S = 65536, N = H = 256, K = I = 256. Both inputs row-major over K (NT).
// fp32 VALU, 64x64 tile, 256 threads, 4x4 micro-tile. Writes into d_out.
// ---------------------------------------------------------------------------
#define TM 64
#define TN 64
#define TK 32

__global__ __launch_bounds__(256) void phase1_gemm(
    const float* __restrict__ x, const float* __restrict__ Wxw,
    const float* __restrict__ Wxb, float* __restrict__ out)
{
    __shared__ __align__(16) float As[TK][TM + 4];  // +4 keeps rows 16B-aligned
    __shared__ __align__(16) float Bs[TK][TN + 4];

    const int t  = threadIdx.x;
    const int tn = t & 15, tm = t >> 4;
    const int m0 = blockIdx.x * TM;
    const int n0 = blockIdx.y * TN;

    float acc[4][4] = {};
    float bias[4];
#pragma unroll
    for (int j = 0; j < 4; ++j) bias[j] = Wxb[n0 + 4 * tn + j];

    // loader mapping: 256 threads, each loads 2 float4 per matrix per K-tile
    const int lr = t >> 3;  // 0..31
    const int lc = t & 7;   // float4 column 0..7 (covers 32 k's)

    for (int kt = 0; kt < I; kt += TK) {
#pragma unroll
        for (int hh = 0; hh < 2; ++hh) {
            const int m = lr + 32 * hh;
            float4 v = *(const float4*)(x   + (size_t)(m0 + m) * I + kt + 4 * lc);
            As[4 * lc + 0][m] = v.x; As[4 * lc + 1][m] = v.y;
            As[4 * lc + 2][m] = v.z; As[4 * lc + 3][m] = v.w;
            float4 w = *(const float4*)(Wxw + (size_t)(n0 + m) * I + kt + 4 * lc);
            Bs[4 * lc + 0][m] = w.x; Bs[4 * lc + 1][m] = w.y;
            Bs[4 * lc + 2][m] = w.z; Bs[4 * lc + 3][m] = w.w;
        }
        __syncthreads();
#pragma unroll
        for (int k = 0; k < TK; ++k) {
            float4 a = *(const float4*)&As[k][4 * tm];
            float4 b = *(const float4*)&Bs[k][4 * tn];
            float av[4] = {a.x, a.y, a.z, a.w};
            float bv[4] = {b.x, b.y, b.z, b.w};
#pragma unroll
            for (int i2 = 0; i2 < 4; ++i2)
#pragma unroll
                for (int j = 0; j < 4; ++j)
                    acc[i2][j] = fmaf(av[i2], bv[j], acc[i2][j]);
        }
        __syncthreads();
    }
#pragma unroll
    for (int i2 = 0; i2 < 4; ++i2) {
        float4 v = { acc[i2][0] + bias[0], acc[i2][1] + bias[1],
                     acc[i2][2] + bias[2], acc[i2][3] + bias[3] };
        *(float4*)(out + (size_t)(m0 + 4 * tm + i2) * H + n0 + 4 * tn) = v;
    }
}

// ---------------------------------------------------------------------------
// Phase 2: per-batch recurrence h = tanh(xw_s + h @ Whw^T), 2048 steps.
// 32 blocks (one per batch), 256 threads. Thread k owns output k and keeps
// Whw[k][0:256] in 128 half2 VGPRs. h lives in LDS (fp16, double-buffered:
// one barrier per step). v_dot2_f32_f16 accumulating in fp32.
// xw is read from d_out (written by phase 1) and overwritten in place with h;
// thread k only ever touches column k -> no cross-thread hazard.
// ---------------------------------------------------------------------------
__global__ __launch_bounds__(256, 1) void phase2_rnn(
    const float* __restrict__ Whw, float* __restrict__ out)
{
    __shared__ __align__(16) _Float16 hbuf[2][H];

    const int b = blockIdx.x;
    const int k = threadIdx.x;

    // Load W row k into registers as fp16 pairs (one-time).
    h2 wreg[H / 2];
    const float4* wp = (const float4*)(Whw + (size_t)k * H);
#pragma unroll
    for (int i = 0; i < H / 4; ++i) {
        float4 f = wp[i];
        wreg[2 * i]     = h2{(_Float16)f.x, (_Float16)f.y};
        wreg[2 * i + 1] = h2{(_Float16)f.z, (_Float16)f.w};
    }

    hbuf[0][k] = (_Float16)0.0f;
    __syncthreads();

    float* outb = out + (size_t)b * S * H + k;
    float xw_cur = outb[0];

    for (int s = 0; s < S; ++s) {
        // prefetch next step's xw while we do this step's MACs
        float xw_nxt = (s + 1 < S) ? outb[(size_t)(s + 1) * H] : 0.0f;

        const h8* hp = (const h8*)hbuf[s & 1];
        float a0 = 0.f, a1 = 0.f, a2 = 0.f, a3 = 0.f;
#pragma unroll
        for (int u = 0; u < H / 8; ++u) {   // 32 iterations, 4 dot2 each
            h8 v = hp[u];
            h2 p0 = {v[0], v[1]};
            h2 p1 = {v[2], v[3]};
            h2 p2 = {v[4], v[5]};
            h2 p3 = {v[6], v[7]};
            a0 = fdot2(wreg[4 * u + 0], p0, a0);
            a1 = fdot2(wreg[4 * u + 1], p1, a1);
            a2 = fdot2(wreg[4 * u + 2], p2, a2);
            a3 = fdot2(wreg[4 * u + 3], p3, a3);
        }
        float hv = tanhf(xw_cur + (a0 + a1) + (a2 + a3));

        outb[(size_t)s * H] = hv;                 // outputs[b,s,k]
        hbuf[(s & 1) ^ 1][k] = (_Float16)hv;      // h for next step
        if (s == S - 1)
            out[(size_t)B * S * H + (size_t)b * H + k] = hv;  // h_last

        __syncthreads();
        xw_cur = xw_nxt;
    }
}

// ---------------------------------------------------------------------------
extern "C" void kernel_launch(void* const* d_in, const int* in_sizes, int n_in,
                              void* d_out, int out_size, void* d_ws, size_t ws_size,
                              hipStream_t stream) {
    const float* x   = (const float*)d_in[0];
    const float* Wxw = (const float*)d_in[1];
    const float* Wxb = (const float*)d_in[2];
    const float* Whw = (const float*)d_in[3];
    float* out = (float*)d_out;

    dim3 g1(B * S / TM, H / TN);   // 1024 x 4
    phase1_gemm<<<g1, 256, 0, stream>>>(x, Wxw, Wxb, out);
    phase2_rnn<<<B, 256, 0, stream>>>(Whw, out);
}